// Round 9
// baseline (1195.927 us; speedup 1.0000x reference)
//
#include <hip/hip_runtime.h>
#include <hip/hip_bf16.h>
#include <math.h>

// Problem constants
#define Bq   128
#define Tq   512
#define Iq   300   // input dim
#define Hq   150   // hidden per dir
#define G3   450   // 3*H
#define Kq   6
#define Cq   300
#define D2   300   // 2*H
#define THq  20
#define CLSq 5

typedef __attribute__((ext_vector_type(8))) short short8;      // 8 bf16 MFMA A/B frag
typedef __attribute__((ext_vector_type(4))) float floatx4;     // MFMA C/D frag
typedef __attribute__((ext_vector_type(2))) _Float16 half2_t;  // packed f16 pair

// fp32 -> bf16 RNE (normal values; matches __float2bfloat16 on this data)
static __device__ __forceinline__ unsigned short f2bf(float f) {
    unsigned int u = __builtin_bit_cast(unsigned int, f);
    u += 0x7FFFu + ((u >> 16) & 1u);
    return (unsigned short)(u >> 16);
}

// f16 packed dot: a.x*b.x + a.y*b.y + c (v_dot2_f32_f16)
static __device__ __forceinline__ float dot2f(half2_t a, half2_t b, float c) {
#if __has_builtin(__builtin_amdgcn_fdot2)
    return __builtin_amdgcn_fdot2(a, b, c, false);
#else
    return c + (float)a.x * (float)b.x + (float)a.y * (float)b.y;
#endif
}

// ---------------------------------------------------------------------------
// Kernel 1: gi GEMM via bf16 MFMA 16x16x32 (R6-proven layouts). R9: reads
// fp32 x/W directly and converts to bf16 during LDS staging (kills the 3
// standalone cast kernels + 118 MB of cast traffic; gi values bit-identical).
// ---------------------------------------------------------------------------
#define LB 40

__global__ __launch_bounds__(256) void gi_gemm_mfma(
    const float* __restrict__ x,      // [B][T][300] fp32
    const float* __restrict__ Wf_,    // [450][300] fp32
    const float* __restrict__ Wb_,
    const float* __restrict__ bf_, const float* __restrict__ bb_,
    float* __restrict__ gic, int t0f, int t0b, int tcShift)
{
    const int dir = blockIdx.z;
    const float* W    = dir ? Wb_ : Wf_;
    const float* bias = dir ? bb_ : bf_;
    const int t0 = dir ? t0b : t0f;
    const int TCr = 1 << tcShift;
    float* outb = gic + (size_t)dir * Bq * TCr * G3;

    const int m0 = blockIdx.y * 128;
    const int n0 = blockIdx.x * 128;
    const int tid  = threadIdx.x;
    const int wv   = tid >> 6, lane = tid & 63;
    const int wm   = wv & 1,  wn   = wv >> 1;
    const int quad = lane >> 4, mr = lane & 15;

    __shared__ __align__(16) unsigned short Ab[128 * LB];
    __shared__ __align__(16) unsigned short Bb[128 * LB];

    floatx4 acc[4][4];
    #pragma unroll
    for (int i = 0; i < 4; ++i)
        #pragma unroll
        for (int j = 0; j < 4; ++j)
            acc[i][j] = (floatx4){0.f, 0.f, 0.f, 0.f};

    for (int k0 = 0; k0 < 320; k0 += 32) {
        __syncthreads();
        #pragma unroll
        for (int i = 0; i < 4; ++i) {
            const int g = tid + 256 * i;         // 0..1023
            const int row = g >> 3, kq = g & 7;  // 4-value granule
            const int k = k0 + kq * 4;
            const int r = m0 + row;
            const int bb2 = r >> tcShift, lt = r & (TCr - 1);
            ushort4 av = make_ushort4(0, 0, 0, 0);
            if (k < Iq) {
                float4 v = *(const float4*)(x + ((size_t)bb2 * Tq + t0 + lt) * Iq + k);
                av = make_ushort4(f2bf(v.x), f2bf(v.y), f2bf(v.z), f2bf(v.w));
            }
            *(ushort4*)&Ab[row * LB + kq * 4] = av;
            const int n = n0 + row;
            ushort4 bv = make_ushort4(0, 0, 0, 0);
            if (n < G3 && k < Iq) {
                float4 v = *(const float4*)(W + (size_t)n * Iq + k);
                bv = make_ushort4(f2bf(v.x), f2bf(v.y), f2bf(v.z), f2bf(v.w));
            }
            *(ushort4*)&Bb[row * LB + kq * 4] = bv;
        }
        __syncthreads();

        short8 af[4], bfr[4];
        #pragma unroll
        for (int i = 0; i < 4; ++i)
            af[i] = *(const short8*)&Ab[(wm * 64 + i * 16 + mr) * LB + quad * 8];
        #pragma unroll
        for (int j = 0; j < 4; ++j)
            bfr[j] = *(const short8*)&Bb[(wn * 64 + j * 16 + mr) * LB + quad * 8];
        #pragma unroll
        for (int i = 0; i < 4; ++i)
            #pragma unroll
            for (int j = 0; j < 4; ++j)
                acc[i][j] = __builtin_amdgcn_mfma_f32_16x16x32_bf16(
                    af[i], bfr[j], acc[i][j], 0, 0, 0);
    }

    #pragma unroll
    for (int j = 0; j < 4; ++j) {
        const int gn = n0 + wn * 64 + j * 16 + mr;
        if (gn >= G3) continue;
        const float bv = bias[gn];
        #pragma unroll
        for (int i = 0; i < 4; ++i) {
            const int mbase = m0 + wm * 64 + i * 16 + quad * 4;
            #pragma unroll
            for (int rg = 0; rg < 4; ++rg)
                outb[(size_t)(mbase + rg) * G3 + gn] = acc[i][j][rg] + bv;
        }
    }
}

// ---------------------------------------------------------------------------
// Kernel 2: GRU recurrence. R9 rationale (R6/R7/R8 falsified LDS-throughput
// model: step time ~2975 cyc invariant across 19->10 reads/lane):
//   (a) NO per-step global load: gi staged in 8-step double-buffered LDS
//       bursts -> barriers drain vmem only once per 8 steps (m97: s_waitcnt
//       vmcnt(0) precedes every s_barrier; was exposed L3/HBM latency/step).
//   (b) f16 packed weights + v_dot2: 4 rows x 20 half2 = 80 VGPR; h is
//       mirrored packed-f16 in LDS by the gate -> gemv = 5 ds_read_b128
//       + 80 fdot2 (half of R8's issue). fp32 h kept for the z*h path.
// Quarter layout as R8: thread t=(rq=t>>2, p=t&3) owns rows 4rq..4rq+3,
// h-cols [38p, 38p+38) (p=3: 36). LDS-partial combine (no shuffles; R7:
// __shfl = ds_bpermute on the LDS pipe, serial rounds regress).
// ---------------------------------------------------------------------------
__global__ __launch_bounds__(512, 2) void gru_rec(
    const float* __restrict__ gic,     // [2][B][TCr][450]
    const float* __restrict__ Whh_f, const float* __restrict__ bhh_f,
    const float* __restrict__ Whh_b, const float* __restrict__ bhh_b,
    float* __restrict__ hstate,        // [2][B][150]
    float* __restrict__ seq,           // [B][T][300]
    int chunk, int tcShift)
{
    const int TCr = 1 << tcShift;
    const int bid = blockIdx.x;
    const int dir = bid & 1;
    const int b   = bid >> 1;
    const float* Whh = dir ? Whh_b : Whh_f;
    const float* bhh = dir ? bhh_b : bhh_f;
    const int tid = threadIdx.x;
    const int rq  = tid >> 2;          // row-quad, valid < 113
    const int p   = tid & 3;           // h-quarter
    const bool gact = (rq < 113);

    __shared__ __align__(16) float stage[32 * 150];        // 18.75 KB: W stage, then 32-step h history
    __shared__ __align__(16) float gib_s[2][8 * 450];      // 28.8 KB: gi double-buffer
    __shared__ __align__(16) float ghp[4][456];            // per-quarter gemv partials
    __shared__ __align__(16) unsigned short h16[160];      // packed-f16 h, 4 x 40 (pads stay 0)
    __shared__ float h32[152];                             // fp32 h (gate's z*h path)

    // weights: w[r][c] = f16{Whh[4rq+r][38p+2c], [38p+2c+1]}, c<19 (p=3: c<18)
    half2_t w[4][20];
    #pragma unroll
    for (int r = 0; r < 4; ++r)
        #pragma unroll
        for (int c = 0; c < 20; ++c)
            w[r][c] = (half2_t)(_Float16)0.f;

    // --- stage Whh through LDS in 32-row chunks; convert owned slice to f16
    for (int c = 0; c < 15; ++c) {
        const int r0 = c * 32;
        const int nrows = (r0 + 32 <= G3) ? 32 : (G3 - r0);
        const int nel = nrows * 150;
        __syncthreads();
        for (int idx = tid * 4; idx < nel; idx += 512 * 4)
            *(float4*)&stage[idx] = *(const float4*)(Whh + (size_t)r0 * 150 + idx);
        __syncthreads();
        if (gact && (rq >> 3) == c) {
            const int rl = 4 * rq - r0;             // 0..28
            const int cmax2 = (p == 3) ? 18 : 19;
            #pragma unroll
            for (int r = 0; r < 4; ++r) {
                const bool rv = (4 * rq + r < G3);
                #pragma unroll
                for (int cc = 0; cc < 19; ++cc) {
                    float f0 = 0.f, f1 = 0.f;
                    if (rv && cc < cmax2) {
                        f0 = stage[(rl + r) * 150 + p * 38 + 2 * cc];
                        f1 = stage[(rl + r) * 150 + p * 38 + 2 * cc + 1];
                    }
                    half2_t hw; hw.x = (_Float16)f0; hw.y = (_Float16)f1;
                    w[r][cc] = hw;
                }
            }
        }
    }

    // gate-lane constants
    float bh3[3] = {0.f, 0.f, 0.f};
    if (tid < Hq) {
        bh3[0] = bhh[tid];
        bh3[1] = bhh[150 + tid];
        bh3[2] = bhh[300 + tid];
    }
    const int pq = tid / 38;                       // for tid<150: 0..3
    const int h16slot = pq * 40 + (tid - pq * 38);

    float* hs = hstate + (size_t)(dir * Bq + b) * Hq;
    if (tid < 160) {
        const int pp = tid / 40, cc = tid % 40;
        const int cmax = (pp == 3) ? 36 : 38;
        const int j = pp * 38 + cc;
        float v = (cc < cmax && chunk > 0) ? hs[j] : 0.f;
        h16[tid] = __builtin_bit_cast(unsigned short, (_Float16)v);
    }
    if (tid < Hq) h32[tid] = (chunk > 0) ? hs[tid] : 0.f;

    const float* gib = gic + (size_t)(dir * Bq + b) * TCr * G3;
    const int t0 = dir ? (Tq - TCr * (chunk + 1)) : (chunk * TCr);
    float* seqb = seq + (size_t)b * Tq * D2 + dir * Hq;

    // gi burst loader: steps sb..sb+7 -> gib_s[buf]
    auto load_burst = [&](int sb, int buf) {
        #pragma unroll
        for (int i = 0; i < 8; ++i) {
            const int idx = tid + i * 512;
            if (idx < 3600) {
                const int ss = idx / 450;
                const int j  = idx - ss * 450;
                const int lt = dir ? (TCr - 1 - (sb + ss)) : (sb + ss);
                gib_s[buf][ss * 450 + j] = gib[(size_t)lt * G3 + j];
            }
        }
    };
    load_burst(0, 0);
    __syncthreads();

    for (int s = 0; s < TCr; ++s) {
        if ((s & 7) == 0 && s + 8 < TCr)
            load_burst(s + 8, ((s >> 3) + 1) & 1);

        if (gact) {
            // this lane's h-quarter: 5 b128 reads = 20 packed-f16 pairs
            const float4* hq = (const float4*)((const unsigned char*)h16 + p * 80);
            const float4 q0 = hq[0], q1 = hq[1], q2 = hq[2], q3 = hq[3], q4 = hq[4];
            half2_t hh[20];
            hh[0]=__builtin_bit_cast(half2_t,q0.x); hh[1]=__builtin_bit_cast(half2_t,q0.y);
            hh[2]=__builtin_bit_cast(half2_t,q0.z); hh[3]=__builtin_bit_cast(half2_t,q0.w);
            hh[4]=__builtin_bit_cast(half2_t,q1.x); hh[5]=__builtin_bit_cast(half2_t,q1.y);
            hh[6]=__builtin_bit_cast(half2_t,q1.z); hh[7]=__builtin_bit_cast(half2_t,q1.w);
            hh[8]=__builtin_bit_cast(half2_t,q2.x); hh[9]=__builtin_bit_cast(half2_t,q2.y);
            hh[10]=__builtin_bit_cast(half2_t,q2.z); hh[11]=__builtin_bit_cast(half2_t,q2.w);
            hh[12]=__builtin_bit_cast(half2_t,q3.x); hh[13]=__builtin_bit_cast(half2_t,q3.y);
            hh[14]=__builtin_bit_cast(half2_t,q3.z); hh[15]=__builtin_bit_cast(half2_t,q3.w);
            hh[16]=__builtin_bit_cast(half2_t,q4.x); hh[17]=__builtin_bit_cast(half2_t,q4.y);
            hh[18]=__builtin_bit_cast(half2_t,q4.z); hh[19]=__builtin_bit_cast(half2_t,q4.w);
            float a0 = 0.f, a1 = 0.f, a2 = 0.f, a3 = 0.f;
            #pragma unroll
            for (int k = 0; k < 20; ++k) {
                a0 = dot2f(w[0][k], hh[k], a0);
                a1 = dot2f(w[1][k], hh[k], a1);
                a2 = dot2f(w[2][k], hh[k], a2);
                a3 = dot2f(w[3][k], hh[k], a3);
            }
            *(float4*)&ghp[p][4 * rq] = make_float4(a0, a1, a2, a3);
        }
        __syncthreads();

        const float* gi_row = &gib_s[(s >> 3) & 1][(s & 7) * 450];
        if (tid < Hq) {
            const float ghr = ghp[0][tid] + ghp[1][tid]
                            + ghp[2][tid] + ghp[3][tid] + bh3[0];
            const float ghz = ghp[0][150+tid] + ghp[1][150+tid]
                            + ghp[2][150+tid] + ghp[3][150+tid] + bh3[1];
            const float ghn = ghp[0][300+tid] + ghp[1][300+tid]
                            + ghp[2][300+tid] + ghp[3][300+tid] + bh3[2];
            const float r = 1.f / (1.f + __expf(-(gi_row[tid]       + ghr)));
            const float z = 1.f / (1.f + __expf(-(gi_row[150 + tid] + ghz)));
            const float nv = tanhf(gi_row[300 + tid] + r * ghn);
            const float hn = (1.f - z) * nv + z * h32[tid];
            h32[tid] = hn;
            h16[h16slot] = __builtin_bit_cast(unsigned short, (_Float16)hn);
            stage[(s & 31) * 150 + tid] = hn;   // LDS history (no per-step global store)
        }
        __syncthreads();

        // cooperative flush of the 32-step h history
        if ((s & 31) == 31 || s == TCr - 1) {
            const int sf0 = s & ~31;
            const int nf2 = (s - sf0 + 1) * 75;        // float2 count
            for (int idx = tid; idx < nf2; idx += 512) {
                const int rrow = idx / 75, cc = idx - rrow * 75;
                const int ssg = sf0 + rrow;
                const int ltw = dir ? (TCr - 1 - ssg) : ssg;
                *(float2*)(seqb + (size_t)(t0 + ltw) * D2 + 2 * cc) =
                    *(const float2*)&stage[rrow * 150 + 2 * cc];
            }
        }
    }

    if (tid < Hq) hs[tid] = h32[tid];
}

// ---------------------------------------------------------------------------
// Kernel 3a: ctxW[k][d] = battn[k][d] + sum_c attn_context[k][c]*Wattn[k][c][d]
// ---------------------------------------------------------------------------
__global__ void ctxw_kernel(
    const float* __restrict__ attn_context,
    const float* __restrict__ Wattn,
    const float* __restrict__ battn,
    float* __restrict__ ctxW)
{
    const int o = blockIdx.x * 256 + threadIdx.x;
    if (o >= Kq * D2) return;
    const int k = o / D2, d = o % D2;
    float acc = battn[o];
    const float* Wp = Wattn + ((size_t)k * (Cq + D2)) * D2 + d;
    for (int c = 0; c < Cq; ++c)
        acc += attn_context[k * Cq + c] * Wp[(size_t)c * D2];
    ctxW[o] = acc;
}

// ---------------------------------------------------------------------------
// Kernel 3b: context[b][k][:] = tanh(ctxW[k] + hidden[b] @ Wattn[k,300:,:])
// ---------------------------------------------------------------------------
__global__ __launch_bounds__(256) void ctx_compute(
    const float* __restrict__ seq,
    const float* __restrict__ Wattn,
    const float* __restrict__ ctxW,
    float* __restrict__ context,      // [B][6][300]
    float* __restrict__ normsq)       // [B][6]
{
    const int b = blockIdx.x;
    const int k = blockIdx.y;
    const int tid = threadIdx.x;
    const int lane = tid & 63, wv = tid >> 6;

    __shared__ float hb[304];
    __shared__ float red[4];

    for (int i = tid; i < D2; i += 256)
        hb[i] = (i < Hq) ? seq[((size_t)b * Tq + (Tq - 1)) * D2 + i]
                         : seq[(size_t)b * Tq * D2 + i];
    __syncthreads();

    float ssq = 0.f;
    for (int d = tid; d < D2; d += 256) {
        float acc = ctxW[k * D2 + d];
        const float* Wp = Wattn + ((size_t)k * (Cq + D2) + Cq) * D2 + d;
        for (int jj = 0; jj < D2; ++jj)
            acc += hb[jj] * Wp[(size_t)jj * D2];
        const float c = tanhf(acc);
        context[((size_t)b * Kq + k) * D2 + d] = c;
        ssq += c * c;
    }
    for (int off = 32; off > 0; off >>= 1) ssq += __shfl_xor(ssq, off, 64);
    if (lane == 0) red[wv] = ssq;
    __syncthreads();
    if (tid == 0) normsq[b * Kq + k] = red[0] + red[1] + red[2] + red[3];
}

// ---------------------------------------------------------------------------
// Kernel 3c: gram regularizer per b
// ---------------------------------------------------------------------------
__global__ __launch_bounds__(256) void gram_kernel(
    const float* __restrict__ context,
    const float* __restrict__ normsq,
    float* __restrict__ regbuf)
{
    const int b = blockIdx.x;
    const int tid = threadIdx.x;
    __shared__ float ctx[Kq * D2];
    __shared__ float Gm[36];

    for (int o = tid; o < Kq * D2; o += 256)
        ctx[o] = context[(size_t)b * Kq * D2 + o];
    __syncthreads();

    if (tid < 36) {
        const int k = tid / 6, jj = tid % 6;
        float g = 0.f;
        for (int d = 0; d < D2; ++d)
            g += ctx[k * D2 + d] * ctx[jj * D2 + d];
        const float nk = fmaxf(sqrtf(normsq[b * Kq + k]), 1e-12f);
        const float nj = fmaxf(sqrtf(normsq[b * Kq + jj]), 1e-12f);
        g /= (nk * nj);
        const float diff = g - ((k == jj) ? 1.f : 0.f);
        Gm[tid] = diff * diff;
    }
    __syncthreads();
    if (tid == 0) {
        float s = 0.f;
        for (int i = 0; i < 36; ++i) s += Gm[i];
        regbuf[b] = sqrtf(s);
    }
}

// ---------------------------------------------------------------------------
// Kernel 4a: energy[b][t][k] = seq[b][t] . context[b][k]   grid (8, B)
// ---------------------------------------------------------------------------
__global__ __launch_bounds__(256) void energy_kernel(
    const float* __restrict__ seq,
    const float* __restrict__ context,
    float* __restrict__ en)           // [B][512][6]
{
    const int tc = blockIdx.x;
    const int b  = blockIdx.y;
    const int tid = threadIdx.x;
    const int lane = tid & 63, wv = tid >> 6;

    __shared__ float ctx[Kq * D2];
    for (int o = tid; o < Kq * D2; o += 256)
        ctx[o] = context[(size_t)b * Kq * D2 + o];
    __syncthreads();

    const float* seqb = seq + (size_t)b * Tq * D2;
    for (int s = 0; s < 16; ++s) {
        const int tt = tc * 64 + s * 4 + wv;
        float acc[Kq] = {0.f,0.f,0.f,0.f,0.f,0.f};
        for (int d = lane; d < D2; d += 64) {
            const float sv = seqb[(size_t)tt * D2 + d];
            #pragma unroll
            for (int k = 0; k < Kq; ++k) acc[k] += sv * ctx[k * D2 + d];
        }
        #pragma unroll
        for (int k = 0; k < Kq; ++k) {
            float v = acc[k];
            for (int off = 32; off > 0; off >>= 1) v += __shfl_xor(v, off, 64);
            if (lane == 0) en[((size_t)b * Tq + tt) * Kq + k] = v;
        }
    }
}

// ---------------------------------------------------------------------------
// Kernel 4b: softmax over t per (b,k), in-place on en.  grid (B)
// ---------------------------------------------------------------------------
__global__ __launch_bounds__(256) void softmax_kernel(float* __restrict__ en)
{
    const int b = blockIdx.x;
    const int tid = threadIdx.x;
    const int lane = tid & 63, wv = tid >> 6;
    __shared__ float es[Tq * Kq];
    __shared__ float red[8];

    for (int o = tid; o < Tq * Kq; o += 256)
        es[o] = en[(size_t)b * Tq * Kq + o];
    __syncthreads();

    for (int k = 0; k < Kq; ++k) {
        float m = -1e30f;
        for (int tt = tid; tt < Tq; tt += 256) m = fmaxf(m, es[tt * Kq + k]);
        for (int off = 32; off > 0; off >>= 1) m = fmaxf(m, __shfl_xor(m, off, 64));
        if (lane == 0) red[wv] = m;
        __syncthreads();
        m = fmaxf(fmaxf(red[0], red[1]), fmaxf(red[2], red[3]));
        float ssum = 0.f;
        for (int tt = tid; tt < Tq; tt += 256) {
            const float e = __expf(es[tt * Kq + k] - m);
            es[tt * Kq + k] = e;
            ssum += e;
        }
        for (int off = 32; off > 0; off >>= 1) ssum += __shfl_xor(ssum, off, 64);
        if (lane == 0) red[4 + wv] = ssum;
        __syncthreads();
        const float inv = 1.f / (red[4] + red[5] + red[6] + red[7]);
        for (int tt = tid; tt < Tq; tt += 256) es[tt * Kq + k] *= inv;
        __syncthreads();
    }

    for (int o = tid; o < Tq * Kq; o += 256)
        en[(size_t)b * Tq * Kq + o] = es[o];
}

// ---------------------------------------------------------------------------
// Kernel 4c: pooled partials over 64-t chunks.  grid (8, B)
// ---------------------------------------------------------------------------
__global__ __launch_bounds__(256) void pooledp_kernel(
    const float* __restrict__ seq,
    const float* __restrict__ en,     // probs now
    float* __restrict__ partial)      // [B*8][1800]
{
    const int tc = blockIdx.x;
    const int b  = blockIdx.y;
    const int tid = threadIdx.x;
    const int lane = tid & 63, wv = tid >> 6;

    __shared__ float pr[64 * Kq];
    __shared__ float part[4][Kq * D2];   // 28.8 KB

    if (tid < 64 * Kq / 2) {
        pr[tid]       = en[((size_t)b * Tq + tc * 64) * Kq + tid];
        pr[tid + 192] = en[((size_t)b * Tq + tc * 64) * Kq + tid + 192];
    }
    __syncthreads();

    const float* seqb = seq + (size_t)b * Tq * D2;

    float pp[Kq][5];
    #pragma unroll
    for (int k = 0; k < Kq; ++k)
        #pragma unroll
        for (int q = 0; q < 5; ++q) pp[k][q] = 0.f;

    for (int s = 0; s < 16; ++s) {
        const int tl = s * 4 + wv;
        const int tt = tc * 64 + tl;
        float prr[Kq];
        #pragma unroll
        for (int k = 0; k < Kq; ++k) prr[k] = pr[tl * Kq + k];
        #pragma unroll
        for (int q = 0; q < 5; ++q) {
            const int d = lane + q * 64;
            const float sv = (d < D2) ? seqb[(size_t)tt * D2 + d] : 0.f;
            #pragma unroll
            for (int k = 0; k < Kq; ++k) pp[k][q] += prr[k] * sv;
        }
    }
    #pragma unroll
    for (int k = 0; k < Kq; ++k)
        #pragma unroll
        for (int q = 0; q < 5; ++q) {
            const int d = lane + q * 64;
            if (d < D2) part[wv][k * D2 + d] = pp[k][q];
        }
    __syncthreads();
    float* op = partial + ((size_t)b * 8 + tc) * (Kq * D2);
    for (int o = tid; o < Kq * D2; o += 256)
        op[o] = part[0][o] + part[1][o] + part[2][o] + part[3][o];
}

// ---------------------------------------------------------------------------
// Kernel 4d: final: pooled reduce -> topic -> logits -> softmax.  grid (B)
// ---------------------------------------------------------------------------
__global__ __launch_bounds__(256) void final_kernel(
    const float* __restrict__ partial,
    const float* __restrict__ Wtop,
    const float* __restrict__ btop,
    const float* __restrict__ Wout,
    const float* __restrict__ bout,
    float* __restrict__ outp)
{
    const int b = blockIdx.x;
    const int tid = threadIdx.x;
    __shared__ float pooled[Kq * D2];
    __shared__ float feats[Kq * THq];
    __shared__ float lsm[8];

    for (int o = tid; o < Kq * D2; o += 256) {
        float s = 0.f;
        #pragma unroll
        for (int c = 0; c < 8; ++c)
            s += partial[((size_t)b * 8 + c) * (Kq * D2) + o];
        pooled[o] = s;
    }
    __syncthreads();

    if (tid < Kq * THq) {
        const int k = tid / THq, hh = tid % THq;
        float acc = btop[tid];
        const float* wp = Wtop + (size_t)k * D2 * THq + hh;
        for (int d = 0; d < D2; ++d)
            acc += pooled[k * D2 + d] * wp[(size_t)d * THq];
        feats[tid] = fmaxf(acc, 0.f);
    }
    __syncthreads();

    if (tid < CLSq) {
        float acc = bout[tid];
        for (int f = 0; f < Kq * THq; ++f)
            acc += feats[f] * Wout[f * CLSq + tid];
        lsm[tid] = acc;
    }
    __syncthreads();
    if (tid < CLSq) {
        float m = lsm[0];
        for (int c = 1; c < CLSq; ++c) m = fmaxf(m, lsm[c]);
        float s = 0.f;
        for (int c = 0; c < CLSq; ++c) s += __expf(lsm[c] - m);
        outp[(size_t)b * CLSq + tid] = __expf(lsm[tid] - m) / s;
    }
}

// ---------------------------------------------------------------------------
// Kernel 5: reg = mean_b regbuf[b]  -> d_out[640]
// ---------------------------------------------------------------------------
__global__ void reg_final(const float* __restrict__ regbuf, float* __restrict__ outp)
{
    const int tid = threadIdx.x;   // 128 threads
    float v = regbuf[tid];
    for (int off = 32; off > 0; off >>= 1) v += __shfl_xor(v, off, 64);
    __shared__ float r2[2];
    if ((tid & 63) == 0) r2[tid >> 6] = v;
    __syncthreads();
    if (tid == 0) outp[Bq * CLSq] = (r2[0] + r2[1]) * (1.f / (float)Bq);
}

// ---------------------------------------------------------------------------
extern "C" void kernel_launch(void* const* d_in, const int* in_sizes, int n_in,
                              void* d_out, int out_size, void* d_ws, size_t ws_size,
                              hipStream_t stream)
{
    const float* x     = (const float*)d_in[0];
    const float* Wih_f = (const float*)d_in[1];
    const float* Whh_f = (const float*)d_in[2];
    const float* bih_f = (const float*)d_in[3];
    const float* bhh_f = (const float*)d_in[4];
    const float* Wih_b = (const float*)d_in[5];
    const float* Whh_b = (const float*)d_in[6];
    const float* bih_b = (const float*)d_in[7];
    const float* bhh_b = (const float*)d_in[8];
    const float* attn_context = (const float*)d_in[9];
    const float* Wattn = (const float*)d_in[10];
    const float* battn = (const float*)d_in[11];
    const float* Wtop  = (const float*)d_in[12];
    const float* btop  = (const float*)d_in[13];
    const float* Wout  = (const float*)d_in[14];
    const float* bout  = (const float*)d_in[15];
    float* outp = (float*)d_out;

    // fixed workspace layout (float units) — no bf16 staging buffers anymore
    float* ws       = (float*)d_ws;
    float* seqv     = ws;                                   // 19,660,800
    float* hstate   = seqv + (size_t)Bq * Tq * D2;          // 38,400
    float* ctxW     = hstate + (size_t)2 * Bq * Hq;         // 1,800
    float* context  = ctxW + Kq * D2;                       // 230,400
    float* regbuf   = context + (size_t)Bq * Kq * D2;       // 128
    float* normsq   = regbuf + Bq;                          // 768
    float* en       = normsq + Bq * Kq;                     // 393,216
    float* partial  = en + (size_t)Bq * Tq * Kq;            // 1,843,200
    float* gi_chunk = partial + (size_t)Bq * 8 * Kq * D2;   // 115200*TCr
    const size_t fixed_floats = (size_t)(gi_chunk - ws);

    // pick largest TCr in {256,128,64,32} that fits ws_size
    int tcShift = 5;
    for (int sh = 8; sh >= 5; --sh) {
        size_t need = (fixed_floats + (size_t)115200 * (1 << sh)) * 4;
        if (need <= ws_size) { tcShift = sh; break; }
    }
    const int TCr = 1 << tcShift;
    const int NL = Tq / TCr;

    for (int c = 0; c < NL; ++c) {
        const int t0f = c * TCr;
        const int t0b = Tq - TCr * (c + 1);
        gi_gemm_mfma<<<dim3(4, Bq * TCr / 128, 2), 256, 0, stream>>>(
            x, Wih_f, Wih_b, bih_f, bih_b, gi_chunk, t0f, t0b, tcShift);
        gru_rec<<<dim3(2 * Bq), 512, 0, stream>>>(
            gi_chunk, Whh_f, bhh_f, Whh_b, bhh_b, hstate, seqv, c, tcShift);
    }

    ctxw_kernel<<<dim3((Kq * D2 + 255) / 256), 256, 0, stream>>>(
        attn_context, Wattn, battn, ctxW);
    ctx_compute<<<dim3(Bq, Kq), 256, 0, stream>>>(seqv, Wattn, ctxW, context, normsq);
    gram_kernel<<<dim3(Bq), 256, 0, stream>>>(context, normsq, regbuf);
    energy_kernel<<<dim3(8, Bq), 256, 0, stream>>>(seqv, context, en);
    softmax_kernel<<<dim3(Bq), 256, 0, stream>>>(en);
    pooledp_kernel<<<dim3(8, Bq), 256, 0, stream>>>(seqv, en, partial);
    final_kernel<<<dim3(Bq), 256, 0, stream>>>(partial, Wtop, btop, Wout, bout, outp);
    reg_final<<<dim3(1), 128, 0, stream>>>(regbuf, outp);
}